// Round 3
// baseline (234.283 us; speedup 1.0000x reference)
//
#include <hip/hip_runtime.h>
#include <hip/hip_bf16.h>
#include <math.h>

#define B_ 64
#define P_ 128
#define C_ 72
#define MROW 104   // m1 LDS row stride in bf16 (208B = 13*16, staggered banks)

typedef __attribute__((ext_vector_type(8))) short short8v;
typedef __attribute__((ext_vector_type(4))) float f32x4;

__device__ __forceinline__ float psi_f(float v) {
    float a = fabsf(v);
    float l = __logf(1.0f + a);
    return copysignf(l, v);
}
__device__ __forceinline__ unsigned pk2bf(float lo, float hi) {
    unsigned a = (unsigned)__builtin_bit_cast(unsigned short, __float2bfloat16(lo));
    unsigned b = (unsigned)__builtin_bit_cast(unsigned short, __float2bfloat16(hi));
    return a | (b << 16);
}
template <int CTRL>
__device__ __forceinline__ float dpp_add(float v) {
    int s = __builtin_amdgcn_mov_dpp(__builtin_bit_cast(int, v), CTRL, 0xF, 0xF, true);
    return v + __builtin_bit_cast(float, s);
}
// full sum across each 16-lane group (fixed tree -> deterministic)
__device__ __forceinline__ float red16(float v) {
    v = dpp_add<0xB1>(v);    // quad_perm(1,0,3,2)  : pair xor1
    v = dpp_add<0x4E>(v);    // quad_perm(2,3,0,1)  : pair xor2
    v = dpp_add<0x141>(v);   // row_half_mirror     : pair quads within 8
    v = dpp_add<0x140>(v);   // row_mirror          : pair 8-groups within 16
    return v;
}

// ---------------- Kernel 1: per-node precompute -------------------------
// A[n][c]  = sum_k h[n][k] * We1[k][c]
// Bc[n][c] = sum_k h[n][k] * We1[72+k][c] + be1[c]
__global__ __launch_bounds__(256) void pre_kernel(
    const float* __restrict__ h, const float* __restrict__ We1,
    const float* __restrict__ be1, float* __restrict__ A, float* __restrict__ Bc)
{
    __shared__ float h_s[16][C_];
    const int n0 = blockIdx.x * 16;
    const int t = threadIdx.x;
    for (int idx = t; idx < 16 * C_; idx += 256)
        ((float*)h_s)[idx] = h[n0 * C_ + idx];
    __syncthreads();

    const int n = t >> 4, c4 = t & 15;
    const int cb = c4 * 4;                 // cols cb..cb+3
    const bool extra = (c4 < 8);
    const int ce = extra ? 64 + c4 : 0;    // extra col (valid idx either way)

    f32x4 aA = {0.f, 0.f, 0.f, 0.f};
    f32x4 aB = *(const f32x4*)&be1[cb];
    float eA = 0.f, eB = be1[ce];

    #pragma unroll 4
    for (int k = 0; k < C_; ++k) {
        float hv = h_s[n][k];
        f32x4 hv4 = {hv, hv, hv, hv};
        const float* rA = We1 + k * C_;
        const float* rB = We1 + (C_ + k) * C_;
        aA = __builtin_elementwise_fma(*(const f32x4*)&rA[cb], hv4, aA);
        aB = __builtin_elementwise_fma(*(const f32x4*)&rB[cb], hv4, aB);
        eA = fmaf(hv, rA[ce], eA);
        eB = fmaf(hv, rB[ce], eB);
    }
    const int nn = n0 + n;
    *(f32x4*)&A[nn * C_ + cb]  = aA;
    *(f32x4*)&Bc[nn * C_ + cb] = aB;
    if (extra) { A[nn * C_ + ce] = eA; Bc[nn * C_ + ce] = eB; }
}

// ---------------- Kernel 2: edge MLP via MFMA ---------------------------
// Block: (b, 16-row i-tile), 8 waves x 512 thr; wave owns 2 i's, loops 8 j-tiles.
__global__ __launch_bounds__(512, 4) void edge_kernel(
    const float* __restrict__ x, const float* __restrict__ A,
    const float* __restrict__ Bc, const float* __restrict__ We1,
    const float* __restrict__ We2, const float* __restrict__ be2,
    const float* __restrict__ Wm, const float* __restrict__ bm,
    const float* __restrict__ Wx,
    float* __restrict__ wm_out, float* __restrict__ xacc_out)
{
    __shared__ __align__(16) float A_s[16][76];
    __shared__ __align__(16) float Bc_s[128][76];
    __shared__ __align__(16) float xj_s[128][4];
    __shared__ __align__(16) float w144_s[C_];
    __shared__ __align__(16) float w145_s[C_];
    __shared__ __align__(16) unsigned short m1_s[8][16][MROW]; // per-wave A-tile

    const int b  = blockIdx.x >> 3;
    const int it = blockIdx.x & 7;
    const int t  = threadIdx.x;
    const int wv = t >> 6;
    const int l  = t & 63;
    const int c16 = l & 15;
    const int g   = l >> 4;

    // ---- stage to LDS ----
    for (int idx = t; idx < 16 * C_; idx += 512) {
        int r = idx / C_, c = idx - r * C_;
        A_s[r][c] = A[(b * P_ + it * 16 + r) * C_ + c];
    }
    for (int idx = t; idx < P_ * C_; idx += 512) {
        int r = idx / C_, c = idx - r * C_;
        Bc_s[r][c] = Bc[(b * P_ + r) * C_ + c];
    }
    for (int idx = t; idx < P_ * 4; idx += 512)
        ((float*)xj_s)[idx] = x[b * P_ * 4 + idx];
    if (t < C_) { w144_s[t] = We1[144 * C_ + t]; w145_s[t] = We1[145 * C_ + t]; }
    __syncthreads();

    // ---- We2 B-fragments in registers: B[k][n], n=nt*16+c16, k=kt*32+g*8+j ----
    short8v Bf[3][5];
    #pragma unroll
    for (int kt = 0; kt < 3; ++kt) {
        #pragma unroll
        for (int nt = 0; nt < 5; ++nt) {
            short8v f;
            #pragma unroll
            for (int jj = 0; jj < 8; ++jj) {
                int k = kt * 32 + g * 8 + jj;
                int n = nt * 16 + c16;
                float w = (k < C_ && n < C_) ? We2[k * C_ + n] : 0.f;
                f[jj] = __builtin_bit_cast(short, __float2bfloat16(w));
            }
            Bf[kt][nt] = f;
        }
    }

    float be2_l[5], Wm_l[5], Wx_l[5];
    #pragma unroll
    for (int nt = 0; nt < 5; ++nt) {
        int c = nt * 16 + c16;
        bool valid = c < C_;
        be2_l[nt] = valid ? be2[c] : 0.f;
        Wm_l[nt]  = valid ? Wm[c]  : 0.f;
        Wx_l[nt]  = valid ? Wx[c]  : 0.f;
    }
    const float bm0 = bm[0];
    const f32x4 zero4 = {0.f, 0.f, 0.f, 0.f};

    // zero k-pad [72..MROW) of this wave's m1 rows (never rewritten)
    {
        short8v z = {0, 0, 0, 0, 0, 0, 0, 0};
        *(short8v*)&m1_s[wv][l >> 2][72 + 8 * (l & 3)] = z;
    }

    #pragma unroll 1
    for (int ii = 0; ii < 2; ++ii) {
        const int iloc = wv * 2 + ii;
        const int i = it * 16 + iloc;
        const int node_i = b * P_ + i;
        const f32x4 xi = *(const f32x4*)&xj_s[i][0];

        float wmacc[5] = {0.f, 0.f, 0.f, 0.f, 0.f};
        f32x4 xacc = zero4;

        #pragma unroll 1
        for (int jt = 0; jt < 8; ++jt) {
            // ---- phase A: m1 -> LDS (lane: edge e=c16, k-chunk by g) ----
            const int e = c16;
            const int j = jt * 16 + e;
            const f32x4 xjv = *(const f32x4*)&xj_s[j][0];
            float d0 = xi[0] - xjv[0], d1 = xi[1] - xjv[1];
            float d2 = xi[2] - xjv[2], d3 = xi[3] - xjv[3];
            float nn = d0 * d0 - d1 * d1 - d2 * d2 - d3 * d3;
            float pp = xi[0] * xjv[0] - xi[1] * xjv[1] - xi[2] * xjv[2] - xi[3] * xjv[3];
            float n_ = psi_f(nn);
            float p_ = psi_f(pp);
            const f32x4 n4 = {n_, n_, n_, n_};
            const f32x4 p4 = {p_, p_, p_, p_};

            const int kbeg = g * 16;
            const int kcnt = (g == 3) ? 24 : 16;
            for (int kk = 0; kk < kcnt; kk += 8) {
                const int k = kbeg + kk;
                f32x4 v0 = *(const f32x4*)&A_s[iloc][k]     + *(const f32x4*)&Bc_s[j][k];
                f32x4 v1 = *(const f32x4*)&A_s[iloc][k + 4] + *(const f32x4*)&Bc_s[j][k + 4];
                v0 = __builtin_elementwise_fma(*(const f32x4*)&w144_s[k],     n4, v0);
                v1 = __builtin_elementwise_fma(*(const f32x4*)&w144_s[k + 4], n4, v1);
                v0 = __builtin_elementwise_fma(*(const f32x4*)&w145_s[k],     p4, v0);
                v1 = __builtin_elementwise_fma(*(const f32x4*)&w145_s[k + 4], p4, v1);
                v0 = __builtin_elementwise_max(v0, zero4);
                v1 = __builtin_elementwise_max(v1, zero4);
                union { short8v v; unsigned u[4]; } pk;
                pk.u[0] = pk2bf(v0[0], v0[1]);
                pk.u[1] = pk2bf(v0[2], v0[3]);
                pk.u[2] = pk2bf(v1[0], v1[1]);
                pk.u[3] = pk2bf(v1[2], v1[3]);
                *(short8v*)&m1_s[wv][e][k] = pk.v;
            }

            // ---- phase B: 15 MFMAs (wave-local LDS, no barrier needed) ----
            f32x4 acc[5] = {};
            #pragma unroll
            for (int kt = 0; kt < 3; ++kt) {
                short8v Af = *(const short8v*)&m1_s[wv][c16][kt * 32 + g * 8];
                #pragma unroll
                for (int nt = 0; nt < 5; ++nt)
                    acc[nt] = __builtin_amdgcn_mfma_f32_16x16x32_bf16(Af, Bf[kt][nt], acc[nt], 0, 0, 0);
            }

            // ---- phase C: epilogue. lane holds m2[row=4g+r][col=nt*16+c16] ----
            f32x4 wdv = zero4, pdv = zero4;
            #pragma unroll
            for (int nt = 0; nt < 5; ++nt) {
                f32x4 m2q = acc[nt] + be2_l[nt];
                m2q = __builtin_elementwise_max(m2q, zero4);
                acc[nt] = m2q;                      // keep relu'd m2
                f32x4 wm4 = {Wm_l[nt], Wm_l[nt], Wm_l[nt], Wm_l[nt]};
                f32x4 wx4 = {Wx_l[nt], Wx_l[nt], Wx_l[nt], Wx_l[nt]};
                wdv = __builtin_elementwise_fma(m2q, wm4, wdv);
                pdv = __builtin_elementwise_fma(m2q, wx4, pdv);
            }
            #pragma unroll
            for (int r = 0; r < 4; ++r) {
                wdv[r] = red16(wdv[r]);
                pdv[r] = red16(pdv[r]);
            }
            #pragma unroll
            for (int r = 0; r < 4; ++r) {
                float w_ = __builtin_amdgcn_rcpf(1.f + __expf(-(wdv[r] + bm0)));
                #pragma unroll
                for (int nt = 0; nt < 5; ++nt)
                    wmacc[nt] = fmaf(w_, acc[nt][r], wmacc[nt]);
                const f32x4 xr = *(const f32x4*)&xj_s[jt * 16 + 4 * g + r][0];
                f32x4 pd4 = {pdv[r], pdv[r], pdv[r], pdv[r]};
                xacc = __builtin_elementwise_fma(pd4, xr, xacc);
            }
        } // jt

        // ---- finalize i: reduce across the 4 row-groups (g) ----
        #pragma unroll
        for (int m = 16; m <= 32; m <<= 1) {
            #pragma unroll
            for (int nt = 0; nt < 5; ++nt) wmacc[nt] += __shfl_xor(wmacc[nt], m, 64);
            #pragma unroll
            for (int q = 0; q < 4; ++q)   xacc[q]   += __shfl_xor(xacc[q], m, 64);
        }
        if (l < 16) {
            #pragma unroll
            for (int nt = 0; nt < 5; ++nt) {
                int c = nt * 16 + l;
                if (c < C_) wm_out[node_i * C_ + c] = wmacc[nt];
            }
        }
        if (l == 0)
            *(f32x4*)&xacc_out[node_i * 4] = xacc;
    } // ii
}

// ---------------- Kernel 3: node MLP + outputs --------------------------
__global__ __launch_bounds__(256) void node_kernel(
    const float* __restrict__ x, const float* __restrict__ h,
    const float* __restrict__ Wh1, const float* __restrict__ bh1,
    const float* __restrict__ Wh2, const float* __restrict__ bh2,
    const float* __restrict__ wm, const float* __restrict__ xacc,
    float* __restrict__ hout, float* __restrict__ xout)
{
    __shared__ float hw_s[16][144];
    __shared__ float g_s[16][C_];
    const int n0 = blockIdx.x * 16;
    const int t = threadIdx.x;

    for (int idx = t; idx < 16 * C_; idx += 256) {
        int n = idx / C_, k = idx - n * C_;
        hw_s[n][k]      = h[(n0 + n) * C_ + k];
        hw_s[n][C_ + k] = wm[(n0 + n) * C_ + k];
    }
    __syncthreads();

    const int n = t >> 4, c4 = t & 15;
    const int cb = 4 * c4;
    const bool extra = (c4 < 8);
    const int ce = extra ? 64 + c4 : 0;
    const f32x4 zero4 = {0.f, 0.f, 0.f, 0.f};

    f32x4 acc = *(const f32x4*)&bh1[cb];
    float eacc = bh1[ce];
    #pragma unroll 4
    for (int k = 0; k < 144; ++k) {
        float hv = hw_s[n][k];
        f32x4 hv4 = {hv, hv, hv, hv};
        const float* row = Wh1 + k * C_;
        acc = __builtin_elementwise_fma(*(const f32x4*)&row[cb], hv4, acc);
        eacc = fmaf(hv, row[ce], eacc);
    }
    acc = __builtin_elementwise_max(acc, zero4);
    eacc = fmaxf(eacc, 0.f);
    *(f32x4*)&g_s[n][cb] = acc;
    if (extra) g_s[n][ce] = eacc;
    __syncthreads();

    f32x4 acc2 = *(const f32x4*)&bh2[cb];
    float e2 = bh2[ce];
    #pragma unroll 4
    for (int k = 0; k < C_; ++k) {
        float gv = g_s[n][k];
        f32x4 gv4 = {gv, gv, gv, gv};
        const float* row = Wh2 + k * C_;
        acc2 = __builtin_elementwise_fma(*(const f32x4*)&row[cb], gv4, acc2);
        e2 = fmaf(gv, row[ce], e2);
    }
    const int nn = n0 + n;
    f32x4 hv4l = *(const f32x4*)&hw_s[n][cb];
    *(f32x4*)&hout[nn * C_ + cb] = hv4l + acc2;
    if (extra) hout[nn * C_ + ce] = hw_s[n][ce] + e2;

    if (t < 64) {
        int nn2 = n0 + (t >> 2), d = t & 3;
        xout[nn2 * 4 + d] = x[nn2 * 4 + d] + 0.005f * (xacc[nn2 * 4 + d] * (1.0f / 128.f));
    }
}

extern "C" void kernel_launch(void* const* d_in, const int* in_sizes, int n_in,
                              void* d_out, int out_size, void* d_ws, size_t ws_size,
                              hipStream_t stream) {
    const float* x   = (const float*)d_in[0];
    const float* h   = (const float*)d_in[1];
    const float* We1 = (const float*)d_in[2];
    const float* be1 = (const float*)d_in[3];
    const float* We2 = (const float*)d_in[4];
    const float* be2 = (const float*)d_in[5];
    const float* Wm  = (const float*)d_in[6];
    const float* bm  = (const float*)d_in[7];
    const float* Wh1 = (const float*)d_in[8];
    const float* bh1 = (const float*)d_in[9];
    const float* Wh2 = (const float*)d_in[10];
    const float* bh2 = (const float*)d_in[11];
    const float* Wx  = (const float*)d_in[12];

    const int NNODE = B_ * P_;               // 8192
    float* A    = (float*)d_ws;              // [8192][72]
    float* Bc   = A  + NNODE * C_;           // [8192][72]
    float* wm   = Bc + NNODE * C_;           // [8192][72]
    float* xacc = wm + NNODE * C_;           // [8192][4]

    float* hout = (float*)d_out;             // [8192][72]
    float* xout = hout + NNODE * C_;         // [8192][4]

    pre_kernel<<<NNODE / 16, 256, 0, stream>>>(h, We1, be1, A, Bc);
    edge_kernel<<<B_ * 8, 512, 0, stream>>>(x, A, Bc, We1, We2, be2,
                                            Wm, bm, Wx, wm, xacc);
    node_kernel<<<NNODE / 16, 256, 0, stream>>>(x, h, Wh1, bh1, Wh2, bh2,
                                                wm, xacc, hout, xout);
}

// Round 4
// 97.381 us; speedup vs baseline: 2.4058x; 2.4058x over previous
//
#include <hip/hip_runtime.h>
#include <hip/hip_bf16.h>
#include <math.h>

#define B_ 64
#define P_ 128
#define C_ 72
#define PADC 80    // f16 global row stride for A/Bc
#define BCS 88     // Bc LDS row stride (176B -> 2-way banks)
#define IT 8       // i-rows per block
#define MROW 104   // m1 LDS row stride in halfs (208B = 13*16)

typedef __attribute__((ext_vector_type(8))) _Float16 half8v;
typedef __attribute__((ext_vector_type(4))) _Float16 half4v;
typedef __attribute__((ext_vector_type(4))) float f32x4;
typedef __attribute__((ext_vector_type(2))) float f32x2;
typedef __attribute__((ext_vector_type(4))) unsigned int u32x4;

__device__ __forceinline__ float psi_f(float v) {
    float a = fabsf(v);
    float l = __logf(1.0f + a);
    return copysignf(l, v);
}
template <int CTRL>
__device__ __forceinline__ float dpp_add(float v) {
    int s = __builtin_amdgcn_update_dpp(0, __builtin_bit_cast(int, v), CTRL, 0xF, 0xF, true);
    return v + __builtin_bit_cast(float, s);
}
// full sum across each 16-lane group (fixed tree -> deterministic)
__device__ __forceinline__ float red16(float v) {
    v = dpp_add<0xB1>(v);    // quad_perm(1,0,3,2)
    v = dpp_add<0x4E>(v);    // quad_perm(2,3,0,1)
    v = dpp_add<0x141>(v);   // row_half_mirror
    v = dpp_add<0x140>(v);   // row_mirror
    return v;
}

// ---------------- Kernel 1: per-node precompute (f16 out, padded 80) ----
__global__ __launch_bounds__(256) void pre_kernel(
    const float* __restrict__ h, const float* __restrict__ We1,
    const float* __restrict__ be1, _Float16* __restrict__ Ah,
    _Float16* __restrict__ Bch)
{
    __shared__ float h_s[16][C_];
    const int n0 = blockIdx.x * 16;
    const int t = threadIdx.x;
    for (int idx = t; idx < 16 * C_; idx += 256)
        ((float*)h_s)[idx] = h[n0 * C_ + idx];
    __syncthreads();

    const int n = t >> 4, c4 = t & 15;
    const int cb = c4 * 4;                 // cols cb..cb+3
    const bool extra = (c4 < 8);
    const int ce = extra ? 64 + c4 : 0;    // source col for extra math

    f32x4 aA = {0.f, 0.f, 0.f, 0.f};
    f32x4 aB = *(const f32x4*)&be1[cb];
    float eA = 0.f, eB = be1[ce];

    #pragma unroll 4
    for (int k = 0; k < C_; ++k) {
        float hv = h_s[n][k];
        f32x4 hv4 = {hv, hv, hv, hv};
        const float* rA = We1 + k * C_;
        const float* rB = We1 + (C_ + k) * C_;
        aA = __builtin_elementwise_fma(*(const f32x4*)&rA[cb], hv4, aA);
        aB = __builtin_elementwise_fma(*(const f32x4*)&rB[cb], hv4, aB);
        eA = fmaf(hv, rA[ce], eA);
        eB = fmaf(hv, rB[ce], eB);
    }
    const int nn = n0 + n;
    _Float16* rowA = Ah + nn * PADC;
    _Float16* rowB = Bch + nn * PADC;
    half4v vA = {(_Float16)aA[0], (_Float16)aA[1], (_Float16)aA[2], (_Float16)aA[3]};
    half4v vB = {(_Float16)aB[0], (_Float16)aB[1], (_Float16)aB[2], (_Float16)aB[3]};
    *(half4v*)&rowA[cb] = vA;
    *(half4v*)&rowB[cb] = vB;
    const int cs = extra ? (64 + c4) : (72 + (c4 - 8));   // cols 64..79 covered
    rowA[cs] = extra ? (_Float16)eA : (_Float16)0.f;
    rowB[cs] = extra ? (_Float16)eB : (_Float16)0.f;
}

// ---------------- Kernel 2: edge MLP via f16 MFMA -----------------------
// Block: (b, 8-row i-tile), 4 waves; wave owns 2 i's, loops 8 j-tiles of 16.
__global__ __launch_bounds__(256, 2) void edge_kernel(
    const float* __restrict__ x, const _Float16* __restrict__ Ah,
    const _Float16* __restrict__ Bch, const float* __restrict__ We1,
    const float* __restrict__ We2, const float* __restrict__ be2,
    const float* __restrict__ Wm, const float* __restrict__ bm,
    const float* __restrict__ Wx,
    float* __restrict__ wm_out, float* __restrict__ xacc_out)
{
    __shared__ __align__(16) _Float16 A_s[IT][PADC];        // 1280 B
    __shared__ __align__(16) _Float16 Bc_s[P_][BCS];        // 22528 B
    __shared__ __align__(16) float xj_s[P_][4];             // 2048 B
    __shared__ __align__(16) _Float16 w1_s[PADC], w2_s[PADC];
    __shared__ __align__(16) _Float16 m1_s[4][16][MROW];    // 13312 B

    const int b  = blockIdx.x >> 4;
    const int it = blockIdx.x & 15;
    const int t  = threadIdx.x;
    const int wv = t >> 6;
    const int l  = t & 63;
    const int c16 = l & 15;
    const int g   = l >> 4;

    // ---- stage to LDS ----
    {
        const unsigned int* Asrc = (const unsigned int*)(Ah + (b * P_ + it * IT) * PADC);
        for (int idx = t; idx < IT * PADC / 2; idx += 256)
            ((unsigned int*)A_s)[idx] = Asrc[idx];
        for (int cidx = t; cidx < P_ * 10; cidx += 256) {
            int r = cidx / 10, c = cidx - r * 10;
            *(u32x4*)&Bc_s[r][c * 8] =
                ((const u32x4*)(Bch + (b * P_ + r) * PADC))[c];
        }
        for (int idx = t; idx < P_ * 4; idx += 256)
            ((float*)xj_s)[idx] = x[b * P_ * 4 + idx];
        if (t < 160) {
            int half_sel = t >= 80;
            int c = t - half_sel * 80;
            float wv_ = (c < C_) ? We1[(144 + half_sel) * C_ + c] : 0.f;
            (half_sel ? w2_s : w1_s)[c] = (_Float16)wv_;
        }
    }
    __syncthreads();

    // ---- We2/be2 B-fragments in registers: B[k][n]; row k=72 carries be2 ----
    half8v Bf[3][5];
    #pragma unroll
    for (int kt = 0; kt < 3; ++kt) {
        #pragma unroll
        for (int nt = 0; nt < 5; ++nt) {
            half8v f;
            #pragma unroll
            for (int jj = 0; jj < 8; ++jj) {
                int k = kt * 32 + g * 8 + jj;
                int n = nt * 16 + c16;
                float w = 0.f;
                if (n < C_) {
                    if (k < C_) w = We2[k * C_ + n];
                    else if (k == C_) w = be2[n];
                }
                f[jj] = (_Float16)w;
            }
            Bf[kt][nt] = f;
        }
    }

    f32x2 WmWx[5];
    #pragma unroll
    for (int nt = 0; nt < 5; ++nt) {
        int c = nt * 16 + c16;
        bool valid = c < C_;
        WmWx[nt][0] = valid ? Wm[c] : 0.f;
        WmWx[nt][1] = valid ? Wx[c] : 0.f;
    }
    const float bm0 = bm[0];
    const f32x4 zero4 = {0.f, 0.f, 0.f, 0.f};

    // init k-pad [72..104): zeros except m1[e][72] = 1.0 (be2 row)
    {
        int row = l >> 2, q = l & 3;
        u32x4 z = {0u, 0u, 0u, 0u};
        if (q == 0) z[0] = 0x00003C00u;    // halfs {1.0, 0} at col 72
        *(u32x4*)&m1_s[wv][row][72 + q * 8] = z;
    }

    #pragma unroll 1
    for (int ii = 0; ii < 2; ++ii) {
        const int iloc = wv * 2 + ii;
        const int i = it * IT + iloc;
        const int node_i = b * P_ + i;
        const f32x4 xi = *(const f32x4*)&xj_s[i][0];

        float wmacc[5] = {0.f, 0.f, 0.f, 0.f, 0.f};
        f32x4 xacc = zero4;

        #pragma unroll 1
        for (int jt = 0; jt < 8; ++jt) {
            // ---- phase A: m1 (fp16 packed) -> LDS ----
            const int j = jt * 16 + c16;
            const f32x4 xjv = *(const f32x4*)&xj_s[j][0];
            float d0 = xi[0] - xjv[0], d1 = xi[1] - xjv[1];
            float d2 = xi[2] - xjv[2], d3 = xi[3] - xjv[3];
            float nn = d0 * d0 - d1 * d1 - d2 * d2 - d3 * d3;
            float pp = xi[0] * xjv[0] - xi[1] * xjv[1] - xi[2] * xjv[2] - xi[3] * xjv[3];
            _Float16 nh = (_Float16)psi_f(nn);
            _Float16 ph = (_Float16)psi_f(pp);
            half8v n8 = {nh, nh, nh, nh, nh, nh, nh, nh};
            half8v p8 = {ph, ph, ph, ph, ph, ph, ph, ph};
            half8v zero8 = {};

            auto processA = [&](int k) {
                half8v a  = *(const half8v*)&A_s[iloc][k];
                half8v bb = *(const half8v*)&Bc_s[j][k];
                half8v w1 = *(const half8v*)&w1_s[k];
                half8v w2 = *(const half8v*)&w2_s[k];
                half8v v = a + bb;
                v = __builtin_elementwise_fma(w1, n8, v);
                v = __builtin_elementwise_fma(w2, p8, v);
                v = __builtin_elementwise_max(v, zero8);
                *(half8v*)&m1_s[wv][c16][k] = v;
            };
            const int kb = g * 16;
            processA(kb);
            processA(kb + 8);
            if (g == 3) processA(64);

            // ---- phase B: 15 f16 MFMAs (wave-local LDS) ----
            f32x4 acc[5] = {};
            #pragma unroll
            for (int kt = 0; kt < 3; ++kt) {
                half8v Af = *(const half8v*)&m1_s[wv][c16][kt * 32 + g * 8];
                #pragma unroll
                for (int nt = 0; nt < 5; ++nt)
                    acc[nt] = __builtin_amdgcn_mfma_f32_16x16x32_f16(Af, Bf[kt][nt], acc[nt], 0, 0, 0);
            }

            // ---- phase C: epilogue (be2 already in acc via k=72 row) ----
            f32x2 wdpd[4] = {};
            #pragma unroll
            for (int nt = 0; nt < 5; ++nt) {
                f32x4 m2q = __builtin_elementwise_max(acc[nt], zero4);
                acc[nt] = m2q;
                #pragma unroll
                for (int r = 0; r < 4; ++r) {
                    f32x2 m2s = {m2q[r], m2q[r]};
                    wdpd[r] = __builtin_elementwise_fma(m2s, WmWx[nt], wdpd[r]);
                }
            }
            #pragma unroll
            for (int r = 0; r < 4; ++r) {
                wdpd[r][0] = red16(wdpd[r][0]);
                wdpd[r][1] = red16(wdpd[r][1]);
            }
            #pragma unroll
            for (int r = 0; r < 4; ++r) {
                float w_ = __builtin_amdgcn_rcpf(1.f + __expf(-(wdpd[r][0] + bm0)));
                #pragma unroll
                for (int nt = 0; nt < 5; ++nt)
                    wmacc[nt] = fmaf(w_, acc[nt][r], wmacc[nt]);
                const f32x4 xr = *(const f32x4*)&xj_s[jt * 16 + 4 * g + r][0];
                f32x4 pd4 = {wdpd[r][1], wdpd[r][1], wdpd[r][1], wdpd[r][1]};
                xacc = __builtin_elementwise_fma(pd4, xr, xacc);
            }
        } // jt

        // ---- finalize i: reduce across the 4 row-groups (g) ----
        #pragma unroll
        for (int m = 16; m <= 32; m <<= 1) {
            #pragma unroll
            for (int nt = 0; nt < 5; ++nt) wmacc[nt] += __shfl_xor(wmacc[nt], m, 64);
            #pragma unroll
            for (int q = 0; q < 4; ++q)   xacc[q]   += __shfl_xor(xacc[q], m, 64);
        }
        if (l < 16) {
            #pragma unroll
            for (int nt = 0; nt < 5; ++nt) {
                int c = nt * 16 + l;
                if (c < C_) wm_out[node_i * C_ + c] = wmacc[nt];
            }
        }
        if (l == 0)
            *(f32x4*)&xacc_out[node_i * 4] = xacc;
    } // ii
}

// ---------------- Kernel 3: node MLP + outputs --------------------------
__global__ __launch_bounds__(256) void node_kernel(
    const float* __restrict__ x, const float* __restrict__ h,
    const float* __restrict__ Wh1, const float* __restrict__ bh1,
    const float* __restrict__ Wh2, const float* __restrict__ bh2,
    const float* __restrict__ wm, const float* __restrict__ xacc,
    float* __restrict__ hout, float* __restrict__ xout)
{
    __shared__ float hw_s[16][144];
    __shared__ float g_s[16][C_];
    const int n0 = blockIdx.x * 16;
    const int t = threadIdx.x;

    for (int idx = t; idx < 16 * C_; idx += 256) {
        int n = idx / C_, k = idx - n * C_;
        hw_s[n][k]      = h[(n0 + n) * C_ + k];
        hw_s[n][C_ + k] = wm[(n0 + n) * C_ + k];
    }
    __syncthreads();

    const int n = t >> 4, c4 = t & 15;
    const int cb = 4 * c4;
    const bool extra = (c4 < 8);
    const int ce = extra ? 64 + c4 : 0;
    const f32x4 zero4 = {0.f, 0.f, 0.f, 0.f};

    f32x4 acc = *(const f32x4*)&bh1[cb];
    float eacc = bh1[ce];
    #pragma unroll 4
    for (int k = 0; k < 144; ++k) {
        float hv = hw_s[n][k];
        f32x4 hv4 = {hv, hv, hv, hv};
        const float* row = Wh1 + k * C_;
        acc = __builtin_elementwise_fma(*(const f32x4*)&row[cb], hv4, acc);
        eacc = fmaf(hv, row[ce], eacc);
    }
    acc = __builtin_elementwise_max(acc, zero4);
    eacc = fmaxf(eacc, 0.f);
    *(f32x4*)&g_s[n][cb] = acc;
    if (extra) g_s[n][ce] = eacc;
    __syncthreads();

    f32x4 acc2 = *(const f32x4*)&bh2[cb];
    float e2 = bh2[ce];
    #pragma unroll 4
    for (int k = 0; k < C_; ++k) {
        float gv = g_s[n][k];
        f32x4 gv4 = {gv, gv, gv, gv};
        const float* row = Wh2 + k * C_;
        acc2 = __builtin_elementwise_fma(*(const f32x4*)&row[cb], gv4, acc2);
        e2 = fmaf(gv, row[ce], e2);
    }
    const int nn = n0 + n;
    f32x4 hv4l = *(const f32x4*)&hw_s[n][cb];
    *(f32x4*)&hout[nn * C_ + cb] = hv4l + acc2;
    if (extra) hout[nn * C_ + ce] = hw_s[n][ce] + e2;

    if (t < 64) {
        int nn2 = n0 + (t >> 2), d = t & 3;
        xout[nn2 * 4 + d] = x[nn2 * 4 + d] + 0.005f * (xacc[nn2 * 4 + d] * (1.0f / 128.f));
    }
}

extern "C" void kernel_launch(void* const* d_in, const int* in_sizes, int n_in,
                              void* d_out, int out_size, void* d_ws, size_t ws_size,
                              hipStream_t stream) {
    const float* x   = (const float*)d_in[0];
    const float* h   = (const float*)d_in[1];
    const float* We1 = (const float*)d_in[2];
    const float* be1 = (const float*)d_in[3];
    const float* We2 = (const float*)d_in[4];
    const float* be2 = (const float*)d_in[5];
    const float* Wm  = (const float*)d_in[6];
    const float* bm  = (const float*)d_in[7];
    const float* Wh1 = (const float*)d_in[8];
    const float* bh1 = (const float*)d_in[9];
    const float* Wh2 = (const float*)d_in[10];
    const float* bh2 = (const float*)d_in[11];
    const float* Wx  = (const float*)d_in[12];

    const int NNODE = B_ * P_;                       // 8192
    _Float16* Ah  = (_Float16*)d_ws;                 // [8192][80] f16
    _Float16* Bch = Ah + NNODE * PADC;               // [8192][80] f16
    float* wm   = (float*)(Bch + NNODE * PADC);      // [8192][72] f32
    float* xacc = wm + NNODE * C_;                   // [8192][4]  f32

    float* hout = (float*)d_out;                     // [8192][72]
    float* xout = hout + NNODE * C_;                 // [8192][4]

    pre_kernel<<<NNODE / 16, 256, 0, stream>>>(h, We1, be1, Ah, Bch);
    edge_kernel<<<B_ * 16, 256, 0, stream>>>(x, Ah, Bch, We1, We2, be2,
                                             Wm, bm, Wx, wm, xacc);
    node_kernel<<<NNODE / 16, 256, 0, stream>>>(x, h, Wh1, bh1, Wh2, bh2,
                                                wm, xacc, hout, xout);
}

// Round 5
// 88.453 us; speedup vs baseline: 2.6487x; 1.1009x over previous
//
#include <hip/hip_runtime.h>
#include <hip/hip_bf16.h>
#include <math.h>

#define B_ 64
#define P_ 128
#define C_ 72
#define PADC 80    // f16 global row stride for A/Bc
#define BCS 88     // LDS row stride in halfs (176B -> 2-way banks, free)
#define IT 8       // i-rows per edge block

typedef __attribute__((ext_vector_type(8))) _Float16 half8v;
typedef __attribute__((ext_vector_type(4))) float f32x4;
typedef __attribute__((ext_vector_type(2))) float f32x2;
typedef __attribute__((ext_vector_type(4))) unsigned int u32x4;

__device__ __forceinline__ float psi_f(float v) {
    float a = fabsf(v);
    return copysignf(__logf(1.0f + a), v);
}
template <int CTRL>
__device__ __forceinline__ float dpp_add(float v) {
    int s = __builtin_amdgcn_update_dpp(0, __builtin_bit_cast(int, v), CTRL, 0xF, 0xF, true);
    return v + __builtin_bit_cast(float, s);
}
// full sum across each 16-lane group (fixed tree -> deterministic)
__device__ __forceinline__ float red16(float v) {
    v = dpp_add<0xB1>(v);    // quad_perm(1,0,3,2)
    v = dpp_add<0x4E>(v);    // quad_perm(2,3,0,1)
    v = dpp_add<0x141>(v);   // row_half_mirror
    v = dpp_add<0x140>(v);   // row_mirror
    return v;
}
__device__ __forceinline__ half8v cvt8(const float* p) {
    f32x4 a = *(const f32x4*)p;
    f32x4 b = *(const f32x4*)(p + 4);
    half8v r = {(_Float16)a[0], (_Float16)a[1], (_Float16)a[2], (_Float16)a[3],
                (_Float16)b[0], (_Float16)b[1], (_Float16)b[2], (_Float16)b[3]};
    return r;
}

// ---------------- Kernel 1: pre (MFMA) ----------------------------------
// [8192x72] @ [72x144] -> A (We1 rows 0..71) and Bc (+be1, rows 72..143), f16.
__global__ __launch_bounds__(256) void pre_kernel(
    const float* __restrict__ h, const float* __restrict__ We1,
    const float* __restrict__ be1, _Float16* __restrict__ Ah,
    _Float16* __restrict__ Bch)
{
    const int t = threadIdx.x;
    const int wv = t >> 6, l = t & 63, c16 = l & 15, g = l >> 4;
    const int m0 = (blockIdx.x * 4 + wv) * 16;

    const float* hrow = h + (m0 + c16) * C_;
    half8v a0 = cvt8(hrow + g * 8);
    half8v a1 = cvt8(hrow + 32 + g * 8);
    half8v a2 = {};
    if (g == 0) a2 = cvt8(hrow + 64);
    else if (g == 1) a2[0] = (_Float16)1.0f;   // bias row k=72

    #pragma unroll 1
    for (int sel = 0; sel < 2; ++sel) {
        f32x4 acc[5] = {};
        #pragma unroll
        for (int kt = 0; kt < 3; ++kt) {
            half8v a = (kt == 0) ? a0 : (kt == 1 ? a1 : a2);
            #pragma unroll
            for (int nt = 0; nt < 5; ++nt) {
                half8v f = {};
                #pragma unroll
                for (int jj = 0; jj < 8; ++jj) {
                    int k = kt * 32 + g * 8 + jj;
                    int n = nt * 16 + c16;
                    float w = 0.f;
                    if (n < C_) {
                        if (k < C_) w = We1[(sel * C_ + k) * C_ + n];
                        else if (k == C_ && sel == 1) w = be1[n];
                    }
                    f[jj] = (_Float16)w;
                }
                acc[nt] = __builtin_amdgcn_mfma_f32_16x16x32_f16(a, f, acc[nt], 0, 0, 0);
            }
        }
        _Float16* dst = sel ? Bch : Ah;
        #pragma unroll
        for (int nt = 0; nt < 5; ++nt) {
            int n = nt * 16 + c16;
            if (n < C_) {
                #pragma unroll
                for (int r = 0; r < 4; ++r)
                    dst[(m0 + 4 * g + r) * PADC + n] = (_Float16)acc[nt][r];
            }
        }
    }
}

// ---------------- Kernel 2: edge MLP, register-direct A-fragments -------
__global__ __launch_bounds__(256, 2) void edge_kernel(
    const float* __restrict__ x, const _Float16* __restrict__ Ah,
    const _Float16* __restrict__ Bch, const float* __restrict__ We1,
    const float* __restrict__ We2, const float* __restrict__ be2,
    const float* __restrict__ Wm, const float* __restrict__ bm,
    const float* __restrict__ Wx,
    float* __restrict__ wm_out, float* __restrict__ xacc_out)
{
    __shared__ __align__(16) _Float16 A_s[IT][PADC];
    __shared__ __align__(16) _Float16 Bc_s[P_][BCS];
    __shared__ __align__(16) float xj_s[P_][4];
    __shared__ __align__(16) _Float16 w1_s[PADC], w2_s[PADC];

    const int b  = blockIdx.x >> 4;
    const int it = blockIdx.x & 15;
    const int t  = threadIdx.x;
    const int wv = t >> 6;
    const int l  = t & 63;
    const int c16 = l & 15;
    const int g   = l >> 4;

    // ---- stage to LDS ----
    {
        const unsigned int* Asrc = (const unsigned int*)(Ah + (b * P_ + it * IT) * PADC);
        for (int idx = t; idx < IT * PADC / 2; idx += 256)
            ((unsigned int*)A_s)[idx] = Asrc[idx];
        for (int cidx = t; cidx < P_ * 10; cidx += 256) {
            int r = cidx / 10, c = cidx - r * 10;
            *(u32x4*)&Bc_s[r][c * 8] = ((const u32x4*)(Bch + (b * P_ + r) * PADC))[c];
        }
        for (int idx = t; idx < P_ * 4; idx += 256)
            ((float*)xj_s)[idx] = x[b * P_ * 4 + idx];
        if (t < 160) {
            int hs = t >= 80;
            int c = t - hs * 80;
            float wv_ = (c < C_) ? We1[(144 + hs) * C_ + c] : 0.f;
            (hs ? w2_s : w1_s)[c] = (_Float16)wv_;
        }
    }
    __syncthreads();

    // ---- We2/be2 B-fragments in registers; row k=72 carries be2 ----
    half8v Bf[3][5];
    #pragma unroll
    for (int kt = 0; kt < 3; ++kt) {
        #pragma unroll
        for (int nt = 0; nt < 5; ++nt) {
            half8v f = {};
            #pragma unroll
            for (int jj = 0; jj < 8; ++jj) {
                int k = kt * 32 + g * 8 + jj;
                int n = nt * 16 + c16;
                float w = 0.f;
                if (n < C_) {
                    if (k < C_) w = We2[k * C_ + n];
                    else if (k == C_) w = be2[n];
                }
                f[jj] = (_Float16)w;
            }
            Bf[kt][nt] = f;
        }
    }

    f32x2 WmWx[5];
    #pragma unroll
    for (int nt = 0; nt < 5; ++nt) {
        int c = nt * 16 + c16;
        bool valid = c < C_;
        WmWx[nt][0] = valid ? Wm[c] : 0.f;
        WmWx[nt][1] = valid ? Wx[c] : 0.f;
    }
    const float bm0 = bm[0];
    const f32x4 zero4 = {0.f, 0.f, 0.f, 0.f};

    #pragma unroll 1
    for (int ii = 0; ii < 2; ++ii) {
        const int iloc = wv * 2 + ii;
        const int i = it * IT + iloc;
        const int node_i = b * P_ + i;
        const f32x4 xi = *(const f32x4*)&xj_s[i][0];

        float wmacc[5] = {0.f, 0.f, 0.f, 0.f, 0.f};
        f32x4 xacc = zero4;

        #pragma unroll 1
        for (int jt = 0; jt < 8; ++jt) {
            // ---- phase A: this lane's A-fragment chunks, in registers ----
            const int j = jt * 16 + c16;
            const f32x4 xjv = *(const f32x4*)&xj_s[j][0];
            float d0 = xi[0] - xjv[0], d1 = xi[1] - xjv[1];
            float d2 = xi[2] - xjv[2], d3 = xi[3] - xjv[3];
            float nn = d0 * d0 - d1 * d1 - d2 * d2 - d3 * d3;
            float pp = xi[0] * xjv[0] - xi[1] * xjv[1] - xi[2] * xjv[2] - xi[3] * xjv[3];
            _Float16 nh = (_Float16)psi_f(nn);
            _Float16 ph = (_Float16)psi_f(pp);
            half8v n8 = {nh, nh, nh, nh, nh, nh, nh, nh};
            half8v p8 = {ph, ph, ph, ph, ph, ph, ph, ph};
            half8v zero8 = {};

            auto chunk = [&](int k) -> half8v {
                half8v av = *(const half8v*)&A_s[iloc][k];
                half8v bv = *(const half8v*)&Bc_s[j][k];
                half8v w1 = *(const half8v*)&w1_s[k];
                half8v w2 = *(const half8v*)&w2_s[k];
                half8v v = av + bv;
                v = __builtin_elementwise_fma(w1, n8, v);
                v = __builtin_elementwise_fma(w2, p8, v);
                return __builtin_elementwise_max(v, zero8);
            };
            half8v af0 = chunk(g * 8);
            half8v af1 = chunk(32 + g * 8);
            half8v af2 = {};
            if (g == 0) af2 = chunk(64);
            else if (g == 1) af2[0] = (_Float16)1.0f;   // be2 bias row k=72

            // ---- phase B: 15 MFMAs straight from registers ----
            f32x4 acc[5] = {};
            #pragma unroll
            for (int nt = 0; nt < 5; ++nt)
                acc[nt] = __builtin_amdgcn_mfma_f32_16x16x32_f16(af0, Bf[0][nt], acc[nt], 0, 0, 0);
            #pragma unroll
            for (int nt = 0; nt < 5; ++nt)
                acc[nt] = __builtin_amdgcn_mfma_f32_16x16x32_f16(af1, Bf[1][nt], acc[nt], 0, 0, 0);
            #pragma unroll
            for (int nt = 0; nt < 5; ++nt)
                acc[nt] = __builtin_amdgcn_mfma_f32_16x16x32_f16(af2, Bf[2][nt], acc[nt], 0, 0, 0);

            // ---- phase C: epilogue ----
            f32x2 wdpd[4] = {};
            #pragma unroll
            for (int nt = 0; nt < 5; ++nt) {
                f32x4 m2q = __builtin_elementwise_max(acc[nt], zero4);
                acc[nt] = m2q;
                #pragma unroll
                for (int r = 0; r < 4; ++r) {
                    f32x2 m2s = {m2q[r], m2q[r]};
                    wdpd[r] = __builtin_elementwise_fma(m2s, WmWx[nt], wdpd[r]);
                }
            }
            #pragma unroll
            for (int r = 0; r < 4; ++r) {
                wdpd[r][0] = red16(wdpd[r][0]);
                wdpd[r][1] = red16(wdpd[r][1]);
            }
            #pragma unroll
            for (int r = 0; r < 4; ++r) {
                float w_ = __builtin_amdgcn_rcpf(1.f + __expf(-(wdpd[r][0] + bm0)));
                #pragma unroll
                for (int nt = 0; nt < 5; ++nt)
                    wmacc[nt] = fmaf(w_, acc[nt][r], wmacc[nt]);
                const f32x4 xr = *(const f32x4*)&xj_s[jt * 16 + 4 * g + r][0];
                f32x4 pd4 = {wdpd[r][1], wdpd[r][1], wdpd[r][1], wdpd[r][1]};
                xacc = __builtin_elementwise_fma(pd4, xr, xacc);
            }
        } // jt

        // ---- finalize i: reduce across the 4 row-groups (g) ----
        #pragma unroll
        for (int m = 16; m <= 32; m <<= 1) {
            #pragma unroll
            for (int nt = 0; nt < 5; ++nt) wmacc[nt] += __shfl_xor(wmacc[nt], m, 64);
            #pragma unroll
            for (int q = 0; q < 4; ++q)   xacc[q]   += __shfl_xor(xacc[q], m, 64);
        }
        if (l < 16) {
            #pragma unroll
            for (int nt = 0; nt < 5; ++nt) {
                int c = nt * 16 + l;
                if (c < C_) wm_out[node_i * C_ + c] = wmacc[nt];
            }
        }
        if (l == 0)
            *(f32x4*)&xacc_out[node_i * 4] = xacc;
    } // ii
}

// ---------------- Kernel 3: node MLP (two chained MFMAs) ----------------
__global__ __launch_bounds__(256) void node_kernel(
    const float* __restrict__ x, const float* __restrict__ h,
    const float* __restrict__ Wh1, const float* __restrict__ bh1,
    const float* __restrict__ Wh2, const float* __restrict__ bh2,
    const float* __restrict__ wm, const float* __restrict__ xacc,
    float* __restrict__ hout, float* __restrict__ xout)
{
    __shared__ _Float16 g_s[4][16][BCS];
    const int t = threadIdx.x;
    const int wv = t >> 6, l = t & 63, c16 = l & 15, g = l >> 4;
    const int m0 = (blockIdx.x * 4 + wv) * 16;

    const float* hrow  = h  + (m0 + c16) * C_;
    const float* wmrow = wm + (m0 + c16) * C_;

    // ---- GEMM1: [h|wm|1] (K=160) @ Wh1(+bh1 row 144) ----
    half8v a[5];
    #pragma unroll
    for (int kt = 0; kt < 5; ++kt) {
        int k = kt * 32 + g * 8;
        half8v v = {};
        if (k < C_) v = cvt8(hrow + k);
        else if (k < 144) v = cvt8(wmrow + (k - C_));
        else if (k == 144) v[0] = (_Float16)1.0f;
        a[kt] = v;
    }
    f32x4 acc1[5] = {};
    #pragma unroll
    for (int kt = 0; kt < 5; ++kt) {
        #pragma unroll
        for (int nt = 0; nt < 5; ++nt) {
            half8v f = {};
            #pragma unroll
            for (int jj = 0; jj < 8; ++jj) {
                int k = kt * 32 + g * 8 + jj;
                int n = nt * 16 + c16;
                float w = 0.f;
                if (n < C_) {
                    if (k < 144) w = Wh1[k * C_ + n];
                    else if (k == 144) w = bh1[n];
                }
                f[jj] = (_Float16)w;
            }
            acc1[nt] = __builtin_amdgcn_mfma_f32_16x16x32_f16(a[kt], f, acc1[nt], 0, 0, 0);
        }
    }
    // relu -> wave-local LDS transpose (D layout -> A-fragment layout)
    #pragma unroll
    for (int nt = 0; nt < 5; ++nt) {
        int n = nt * 16 + c16;
        #pragma unroll
        for (int r = 0; r < 4; ++r)
            g_s[wv][4 * g + r][n] = (_Float16)fmaxf(acc1[nt][r], 0.f);
    }
    half8v b0 = *(const half8v*)&g_s[wv][c16][g * 8];
    half8v b1 = *(const half8v*)&g_s[wv][c16][32 + g * 8];
    half8v b2 = {};
    if (g == 0) b2 = *(const half8v*)&g_s[wv][c16][64];
    else if (g == 1) b2[0] = (_Float16)1.0f;   // bh2 bias row k=72

    // ---- GEMM2: g (K=96) @ Wh2(+bh2 row 72) ----
    f32x4 acc2[5] = {};
    #pragma unroll
    for (int kt = 0; kt < 3; ++kt) {
        half8v aa = (kt == 0) ? b0 : (kt == 1 ? b1 : b2);
        #pragma unroll
        for (int nt = 0; nt < 5; ++nt) {
            half8v f = {};
            #pragma unroll
            for (int jj = 0; jj < 8; ++jj) {
                int k = kt * 32 + g * 8 + jj;
                int n = nt * 16 + c16;
                float w = 0.f;
                if (n < C_) {
                    if (k < C_) w = Wh2[k * C_ + n];
                    else if (k == C_) w = bh2[n];
                }
                f[jj] = (_Float16)w;
            }
            acc2[nt] = __builtin_amdgcn_mfma_f32_16x16x32_f16(aa, f, acc2[nt], 0, 0, 0);
        }
    }
    #pragma unroll
    for (int nt = 0; nt < 5; ++nt) {
        int n = nt * 16 + c16;
        if (n < C_) {
            #pragma unroll
            for (int r = 0; r < 4; ++r) {
                int row = m0 + 4 * g + r;
                hout[row * C_ + n] = h[row * C_ + n] + acc2[nt][r];
            }
        }
    }
    // xout: this block covers rows blockIdx.x*64 .. +63
    {
        int row = blockIdx.x * 64 + (t >> 2), d = t & 3;
        xout[row * 4 + d] = x[row * 4 + d] + 0.005f * (xacc[row * 4 + d] * (1.0f / 128.f));
    }
}

extern "C" void kernel_launch(void* const* d_in, const int* in_sizes, int n_in,
                              void* d_out, int out_size, void* d_ws, size_t ws_size,
                              hipStream_t stream) {
    const float* x   = (const float*)d_in[0];
    const float* h   = (const float*)d_in[1];
    const float* We1 = (const float*)d_in[2];
    const float* be1 = (const float*)d_in[3];
    const float* We2 = (const float*)d_in[4];
    const float* be2 = (const float*)d_in[5];
    const float* Wm  = (const float*)d_in[6];
    const float* bm  = (const float*)d_in[7];
    const float* Wh1 = (const float*)d_in[8];
    const float* bh1 = (const float*)d_in[9];
    const float* Wh2 = (const float*)d_in[10];
    const float* bh2 = (const float*)d_in[11];
    const float* Wx  = (const float*)d_in[12];

    const int NNODE = B_ * P_;                       // 8192
    _Float16* Ah  = (_Float16*)d_ws;                 // [8192][80] f16
    _Float16* Bch = Ah + NNODE * PADC;               // [8192][80] f16
    float* wm   = (float*)(Bch + NNODE * PADC);      // [8192][72] f32
    float* xacc = wm + NNODE * C_;                   // [8192][4]  f32

    float* hout = (float*)d_out;                     // [8192][72]
    float* xout = hout + NNODE * C_;                 // [8192][4]

    pre_kernel<<<NNODE / 64, 256, 0, stream>>>(h, We1, be1, Ah, Bch);
    edge_kernel<<<B_ * 16, 256, 0, stream>>>(x, Ah, Bch, We1, We2, be2,
                                             Wm, bm, Wx, wm, xacc);
    node_kernel<<<NNODE / 64, 256, 0, stream>>>(x, h, Wh1, bh1, Wh2, bh2,
                                                wm, xacc, hout, xout);
}